// Round 1
// baseline (1160.929 us; speedup 1.0000x reference)
//
#include <hip/hip_runtime.h>
#include <hip/hip_bf16.h>
#include <math.h>

#define N_TOK 2048
#define DIMX  1024
#define NEXP  8
#define HID   4096

typedef __attribute__((ext_vector_type(8))) short short8;
typedef __attribute__((ext_vector_type(4))) float f32x4;

__device__ __forceinline__ unsigned short f2bf(float f) {
  unsigned int u = __float_as_uint(f);
  u += 0x7fff + ((u >> 16) & 1);   // RTNE
  return (unsigned short)(u >> 16);
}

// ---------------- ws layout (bytes) ----------------
#define WS_COUNTS   0        // 8  i32  (zeroed)
#define WS_CNTSE    64       // 16 i32  (zeroed)
#define WS_OFFS     192      // 9  i32
#define WS_INCL     256      // 16 i32
#define WS_CBUF     1024     // 8*1024 f32 (zeroed; atomic accumulated)
#define WS_SV       33792    // 2*1024 f32
#define WS_EARR     49152    // 2048*2 i32
#define WS_WARR     65536    // 2048*2 f32
#define WS_POS      81920    // 2048*2 i32
#define WS_TTOK     98304    // 4096 i32
#define WS_TW       114688   // 4096 f32
#define WS_G        131072   // (4096+64)*4096 bf16 = ~34 MB
#define WS_ZERO_BYTES 33792  // counts+cntse+cbuf region

// ---------------- router (f64 for selection robustness) ----------------
__global__ __launch_bounds__(256) void k_router(const float* __restrict__ x,
                                                const float* __restrict__ Wr,
                                                const float* __restrict__ br,
                                                char* ws) {
  int* counts = (int*)(ws + WS_COUNTS);
  int* cntse  = (int*)(ws + WS_CNTSE);
  int* eArr   = (int*)(ws + WS_EARR);
  float* wArr = (float*)(ws + WS_WARR);
  int* posArr = (int*)(ws + WS_POS);

  int wid  = threadIdx.x >> 6;
  int lane = threadIdx.x & 63;
  int n = blockIdx.x * 4 + wid;

  double acc[NEXP];
#pragma unroll
  for (int e = 0; e < NEXP; e++) acc[e] = 0.0;
  const float* xr = x + (size_t)n * DIMX;
  for (int i = 0; i < DIMX / 64; i++) {
    int kk = i * 64 + lane;
    double xv = (double)xr[kk];
    const float* wr = Wr + (size_t)kk * NEXP;
#pragma unroll
    for (int e = 0; e < NEXP; e++) acc[e] += xv * (double)wr[e];
  }
#pragma unroll
  for (int e = 0; e < NEXP; e++) {
    for (int off = 32; off > 0; off >>= 1)
      acc[e] += __shfl_down(acc[e], off, 64);
  }
  if (lane == 0) {
    double l[NEXP], p[NEXP];
    double m = -1e300;
#pragma unroll
    for (int e = 0; e < NEXP; e++) { l[e] = acc[e] + (double)br[e]; m = fmax(m, l[e]); }
    double s = 0.0;
#pragma unroll
    for (int e = 0; e < NEXP; e++) { p[e] = exp(l[e] - m); s += p[e]; }
    double inv = 1.0 / s;
#pragma unroll
    for (int e = 0; e < NEXP; e++) p[e] *= inv;
    // top-2, lowest index wins ties (jax.lax.top_k semantics)
    int e0 = 0;
    for (int e = 1; e < NEXP; e++) if (p[e] > p[e0]) e0 = e;
    int e1 = -1;
    for (int e = 0; e < NEXP; e++) { if (e == e0) continue; if (e1 < 0 || p[e] > p[e1]) e1 = e; }

    int pos0 = atomicAdd(&counts[e0], 1);
    int pos1 = atomicAdd(&counts[e1], 1);
    atomicAdd(&cntse[0 * NEXP + e0], 1);
    atomicAdd(&cntse[1 * NEXP + e1], 1);
    eArr[n * 2 + 0] = e0;  eArr[n * 2 + 1] = e1;
    wArr[n * 2 + 0] = (float)p[e0];  wArr[n * 2 + 1] = (float)p[e1];
    posArr[n * 2 + 0] = pos0;  posArr[n * 2 + 1] = pos1;
  }
}

// ---------------- prefix + include flags ----------------
__global__ void k_prefix(char* ws) {
  int* counts = (int*)(ws + WS_COUNTS);
  int* cntse  = (int*)(ws + WS_CNTSE);
  int* offs   = (int*)(ws + WS_OFFS);
  int* incl   = (int*)(ws + WS_INCL);
  if (threadIdx.x == 0) {
    int o = 0;
    for (int e = 0; e < NEXP; e++) { offs[e] = o; o += counts[e]; }
    offs[NEXP] = o;
  }
  if (threadIdx.x < 16) incl[threadIdx.x] = (cntse[threadIdx.x] > 0) ? 1 : 0;
}

// ---------------- scatter task lists ----------------
__global__ __launch_bounds__(256) void k_scatter(char* ws) {
  int* eArr   = (int*)(ws + WS_EARR);
  float* wArr = (float*)(ws + WS_WARR);
  int* posArr = (int*)(ws + WS_POS);
  int* offs   = (int*)(ws + WS_OFFS);
  int* ttok   = (int*)(ws + WS_TTOK);
  float* tw   = (float*)(ws + WS_TW);
  int n = blockIdx.x * 256 + threadIdx.x;
  if (n >= N_TOK) return;
#pragma unroll
  for (int s = 0; s < 2; s++) {
    int e = eArr[n * 2 + s];
    int t = offs[e] + posArr[n * 2 + s];
    ttok[t] = n;
    tw[t] = wArr[n * 2 + s];
  }
}

// ---------------- c_e = relu(b1_e) @ W2_e + b2_e  (f32, atomic partials) ----------------
__global__ __launch_bounds__(256) void k_cvec(const float* __restrict__ W2,
                                              const float* __restrict__ b1,
                                              const float* __restrict__ b2,
                                              char* ws) {
  float* cbuf = (float*)(ws + WS_CBUF);
  int e = blockIdx.y;
  int d = blockIdx.x * 256 + threadIdx.x;
  int h0 = blockIdx.z * 512;
  __shared__ float rb[512];
  for (int h = threadIdx.x; h < 512; h += 256) rb[h] = fmaxf(b1[(size_t)e * HID + h0 + h], 0.f);
  __syncthreads();
  float acc = (blockIdx.z == 0) ? b2[(size_t)e * DIMX + d] : 0.f;
  const float* w = W2 + (size_t)e * HID * DIMX + (size_t)h0 * DIMX + d;
#pragma unroll 8
  for (int h = 0; h < 512; h++) acc += rb[h] * w[(size_t)h * DIMX];
  atomicAdd(&cbuf[e * DIMX + d], acc);
}

// ---------------- Sv[s] = sum of included c_e ----------------
__global__ __launch_bounds__(256) void k_sv(char* ws) {
  float* cbuf = (float*)(ws + WS_CBUF);
  float* sv   = (float*)(ws + WS_SV);
  int* incl   = (int*)(ws + WS_INCL);
  int i = blockIdx.x * 256 + threadIdx.x;   // 0..2047
  int s = i >> 10, d = i & 1023;
  float acc = 0.f;
#pragma unroll
  for (int e = 0; e < NEXP; e++) if (incl[s * NEXP + e]) acc += cbuf[e * DIMX + d];
  sv[i] = acc;
}

// ---------------- out baseline: out[n] = w0*Sv[0] + w1*Sv[1] ----------------
__global__ __launch_bounds__(256) void k_base(char* ws, float* __restrict__ out) {
  float* wArr = (float*)(ws + WS_WARR);
  float* sv   = (float*)(ws + WS_SV);
  int n = blockIdx.x;
  float w0 = wArr[n * 2], w1 = wArr[n * 2 + 1];
  for (int d = threadIdx.x; d < DIMX; d += 256)
    out[(size_t)n * DIMX + d] = w0 * sv[d] + w1 * sv[DIMX + d];
}

// ---------------- GEMM1: g = relu(x@W1+b1) - relu(b1), bf16 out ----------------
__global__ __launch_bounds__(256) void k_gemm1(const float* __restrict__ x,
                                               const float* __restrict__ W1,
                                               const float* __restrict__ b1,
                                               char* ws) {
  int* offs = (int*)(ws + WS_OFFS);
  int* ttok = (int*)(ws + WS_TTOK);
  unsigned short* g = (unsigned short*)(ws + WS_G);

  int e = blockIdx.z;
  int off = offs[e];
  int cnt = offs[e + 1] - off;
  int m0 = blockIdx.x * 64;
  if (m0 >= cnt) return;
  int n0 = blockIdx.y * 64;

  __shared__ __align__(16) unsigned short As[64][40];
  __shared__ __align__(16) unsigned short Bs[64][40];

  int tid = threadIdx.x;
  int lane = tid & 63;
  int wid = tid >> 6;
  int wm = wid >> 1, wn = wid & 1;

  // A staging mapping: 64 rows x 32 k, 8 f32 per thread
  int ar = tid >> 2;
  int akc = (tid & 3) * 8;
  int arow = m0 + ar;
  int tok = (arow < cnt) ? ttok[off + arow] : 0;
  const float* aptr = x + (size_t)tok * DIMX;
  // B staging mapping: thread gathers 8 k's of one column j (transpose into LDS)
  int bj = tid & 63;
  int bk = (tid >> 6) * 8;
  const float* bbase = W1 + (size_t)e * DIMX * HID + n0 + bj;

  f32x4 acc[2][2];
#pragma unroll
  for (int i = 0; i < 2; i++)
#pragma unroll
    for (int j = 0; j < 2; j++) acc[i][j] = (f32x4)0.f;

  int kg = (lane >> 4) * 8;
  int rsel = lane & 15;

  for (int ks = 0; ks < DIMX; ks += 32) {
    float4 a0 = *(const float4*)(aptr + ks + akc);
    float4 a1 = *(const float4*)(aptr + ks + akc + 4);
    short8 av;
    av[0] = (short)f2bf(a0.x); av[1] = (short)f2bf(a0.y);
    av[2] = (short)f2bf(a0.z); av[3] = (short)f2bf(a0.w);
    av[4] = (short)f2bf(a1.x); av[5] = (short)f2bf(a1.y);
    av[6] = (short)f2bf(a1.z); av[7] = (short)f2bf(a1.w);
    *(short8*)&As[ar][akc] = av;

    short8 bv;
#pragma unroll
    for (int i = 0; i < 8; i++)
      bv[i] = (short)f2bf(bbase[(size_t)(ks + bk + i) * HID]);
    *(short8*)&Bs[bj][bk] = bv;

    __syncthreads();
    short8 af0 = *(short8*)&As[wm * 32 + rsel][kg];
    short8 af1 = *(short8*)&As[wm * 32 + 16 + rsel][kg];
    short8 bf0 = *(short8*)&Bs[wn * 32 + rsel][kg];
    short8 bf1 = *(short8*)&Bs[wn * 32 + 16 + rsel][kg];
    acc[0][0] = __builtin_amdgcn_mfma_f32_16x16x32_bf16(af0, bf0, acc[0][0], 0, 0, 0);
    acc[0][1] = __builtin_amdgcn_mfma_f32_16x16x32_bf16(af0, bf1, acc[0][1], 0, 0, 0);
    acc[1][0] = __builtin_amdgcn_mfma_f32_16x16x32_bf16(af1, bf0, acc[1][0], 0, 0, 0);
    acc[1][1] = __builtin_amdgcn_mfma_f32_16x16x32_bf16(af1, bf1, acc[1][1], 0, 0, 0);
    __syncthreads();
  }

  int crow = (lane >> 4) * 4;
  int ccol = lane & 15;
#pragma unroll
  for (int fn = 0; fn < 2; fn++) {
    int j = n0 + wn * 32 + fn * 16 + ccol;
    float b1v = b1[(size_t)e * HID + j];
    float rb = fmaxf(b1v, 0.f);
#pragma unroll
    for (int fm = 0; fm < 2; fm++) {
#pragma unroll
      for (int r = 0; r < 4; r++) {
        int m = m0 + wm * 32 + fm * 16 + crow + r;
        if (m < cnt) {
          float v = fmaxf(acc[fm][fn][r] + b1v, 0.f) - rb;
          g[(size_t)(off + m) * HID + j] = f2bf(v);
        }
      }
    }
  }
}

// ---------------- GEMM2: out[tok] += w * (g @ W2_e) ----------------
__global__ __launch_bounds__(256) void k_gemm2(const float* __restrict__ W2,
                                               char* ws, float* __restrict__ out) {
  int* offs = (int*)(ws + WS_OFFS);
  int* ttok = (int*)(ws + WS_TTOK);
  float* tw = (float*)(ws + WS_TW);
  const unsigned short* g = (const unsigned short*)(ws + WS_G);

  int e = blockIdx.z;
  int off = offs[e];
  int cnt = offs[e + 1] - off;
  int m0 = blockIdx.x * 64;
  if (m0 >= cnt) return;
  int n0 = blockIdx.y * 64;

  __shared__ __align__(16) unsigned short As[64][40];
  __shared__ __align__(16) unsigned short Bs[64][40];

  int tid = threadIdx.x;
  int lane = tid & 63;
  int wid = tid >> 6;
  int wm = wid >> 1, wn = wid & 1;

  int ar = tid >> 2;
  int akc = (tid & 3) * 8;
  const unsigned short* aptr = g + (size_t)(off + m0 + ar) * HID;
  int bj = tid & 63;
  int bk = (tid >> 6) * 8;
  const float* bbase = W2 + (size_t)e * HID * DIMX + n0 + bj;

  f32x4 acc[2][2];
#pragma unroll
  for (int i = 0; i < 2; i++)
#pragma unroll
    for (int j = 0; j < 2; j++) acc[i][j] = (f32x4)0.f;

  int kg = (lane >> 4) * 8;
  int rsel = lane & 15;

  for (int ks = 0; ks < HID; ks += 32) {
    short8 av = *(const short8*)(aptr + ks + akc);
    *(short8*)&As[ar][akc] = av;
    short8 bv;
#pragma unroll
    for (int i = 0; i < 8; i++)
      bv[i] = (short)f2bf(bbase[(size_t)(ks + bk + i) * DIMX]);
    *(short8*)&Bs[bj][bk] = bv;

    __syncthreads();
    short8 af0 = *(short8*)&As[wm * 32 + rsel][kg];
    short8 af1 = *(short8*)&As[wm * 32 + 16 + rsel][kg];
    short8 bf0 = *(short8*)&Bs[wn * 32 + rsel][kg];
    short8 bf1 = *(short8*)&Bs[wn * 32 + 16 + rsel][kg];
    acc[0][0] = __builtin_amdgcn_mfma_f32_16x16x32_bf16(af0, bf0, acc[0][0], 0, 0, 0);
    acc[0][1] = __builtin_amdgcn_mfma_f32_16x16x32_bf16(af0, bf1, acc[0][1], 0, 0, 0);
    acc[1][0] = __builtin_amdgcn_mfma_f32_16x16x32_bf16(af1, bf0, acc[1][0], 0, 0, 0);
    acc[1][1] = __builtin_amdgcn_mfma_f32_16x16x32_bf16(af1, bf1, acc[1][1], 0, 0, 0);
    __syncthreads();
  }

  int crow = (lane >> 4) * 4;
  int ccol = lane & 15;
#pragma unroll
  for (int fm = 0; fm < 2; fm++) {
#pragma unroll
    for (int r = 0; r < 4; r++) {
      int m = m0 + wm * 32 + fm * 16 + crow + r;
      if (m < cnt) {
        int tok = ttok[off + m];
        float w = tw[off + m];
#pragma unroll
        for (int fn = 0; fn < 2; fn++) {
          int j = n0 + wn * 32 + fn * 16 + ccol;
          atomicAdd(&out[(size_t)tok * DIMX + j], w * acc[fm][fn][r]);
        }
      }
    }
  }
}

extern "C" void kernel_launch(void* const* d_in, const int* in_sizes, int n_in,
                              void* d_out, int out_size, void* d_ws, size_t ws_size,
                              hipStream_t stream) {
  const float* x  = (const float*)d_in[0];
  const float* Wr = (const float*)d_in[1];
  const float* br = (const float*)d_in[2];
  const float* W1 = (const float*)d_in[3];
  const float* b1 = (const float*)d_in[4];
  const float* W2 = (const float*)d_in[5];
  const float* b2 = (const float*)d_in[6];
  float* out = (float*)d_out;
  char* ws = (char*)d_ws;

  hipMemsetAsync(ws, 0, WS_ZERO_BYTES, stream);
  k_router<<<N_TOK / 4, 256, 0, stream>>>(x, Wr, br, ws);
  k_prefix<<<1, 64, 0, stream>>>(ws);
  k_scatter<<<N_TOK / 256, 256, 0, stream>>>(ws);
  k_cvec<<<dim3(4, NEXP, 8), 256, 0, stream>>>(W2, b1, b2, ws);
  k_sv<<<8, 256, 0, stream>>>(ws);
  k_base<<<N_TOK, 256, 0, stream>>>(ws, out);
  k_gemm1<<<dim3(32, HID / 64, NEXP), 256, 0, stream>>>(x, W1, b1, ws);
  k_gemm2<<<dim3(32, DIMX / 64, NEXP), 256, 0, stream>>>(W2, ws, out);
}

// Round 5
// 1112.098 us; speedup vs baseline: 1.0439x; 1.0439x over previous
//
#include <hip/hip_runtime.h>
#include <hip/hip_bf16.h>
#include <math.h>

#define N_TOK 2048
#define DIMX  1024
#define NEXP  8
#define HID   4096

typedef __attribute__((ext_vector_type(8))) short short8;
typedef __attribute__((ext_vector_type(4))) float f32x4;
typedef unsigned short ushortT;

__device__ __forceinline__ unsigned short f2bf(float f) {
  unsigned int u = __float_as_uint(f);
  u += 0x7fff + ((u >> 16) & 1);   // RTNE
  return (unsigned short)(u >> 16);
}
__device__ __forceinline__ float bf2f(unsigned short u) {
  return __uint_as_float(((unsigned)u) << 16);
}
__device__ __forceinline__ void gl16(const void* g, void* l) {
  __builtin_amdgcn_global_load_lds((const __attribute__((address_space(1))) unsigned*)g,
                                   (__attribute__((address_space(3))) unsigned*)l, 16, 0, 0);
}

// ---------------- ws layout (bytes) ----------------
#define WS_COUNTS   0        // 8  i32  (zeroed)
#define WS_CNTSE    64       // 16 i32  (zeroed)
#define WS_OFFS     192      // 9  i32
#define WS_INCL     256      // 16 i32
#define WS_CBUF     1024     // 8*1024 f32 (fallback: atomic, zeroed)
#define WS_SV       33792    // 2*1024 f32
#define WS_EARR     49152    // 2048*2 i32
#define WS_WARR     65536    // 2048*2 f32
#define WS_POS      81920    // 2048*2 i32
#define WS_TTOK     98304    // 4096 i32
#define WS_TW       114688   // 4096 f32
#define WS_G_F      131072   // fallback g: (4096+64)*4096 bf16
// fast-path buffers
#define WS_XBF      4194304ull                     // 2048*1024 bf16 = 4 MB
#define WS_W1T      8388608ull                     // 8*4096*1024 bf16 = 64 MB
#define WS_W2T      75497472ull                    // 8*1024*4096 bf16 = 64 MB
#define WS_G        142606336ull                   // 4224*4096 bf16 = 34.6 MB
#define WS_Y2       177209344ull                   // 2*4224*1024 f32 = 34.6 MB
#define WS_NEED     211812352ull
#define WS_ZERO_BYTES 33792

// ---------------- router (f64 for selection robustness) ----------------
__global__ __launch_bounds__(256) void k_router(const float* __restrict__ x,
                                                const float* __restrict__ Wr,
                                                const float* __restrict__ br,
                                                char* ws) {
  int* counts = (int*)(ws + WS_COUNTS);
  int* cntse  = (int*)(ws + WS_CNTSE);
  int* eArr   = (int*)(ws + WS_EARR);
  float* wArr = (float*)(ws + WS_WARR);
  int* posArr = (int*)(ws + WS_POS);

  int wid  = threadIdx.x >> 6;
  int lane = threadIdx.x & 63;
  int n = blockIdx.x * 4 + wid;

  double acc[NEXP];
#pragma unroll
  for (int e = 0; e < NEXP; e++) acc[e] = 0.0;
  const float* xr = x + (size_t)n * DIMX;
  for (int i = 0; i < DIMX / 64; i++) {
    int kk = i * 64 + lane;
    double xv = (double)xr[kk];
    const float* wr = Wr + (size_t)kk * NEXP;
#pragma unroll
    for (int e = 0; e < NEXP; e++) acc[e] += xv * (double)wr[e];
  }
#pragma unroll
  for (int e = 0; e < NEXP; e++) {
    for (int off = 32; off > 0; off >>= 1)
      acc[e] += __shfl_down(acc[e], off, 64);
  }
  if (lane == 0) {
    double l[NEXP], p[NEXP];
    double m = -1e300;
#pragma unroll
    for (int e = 0; e < NEXP; e++) { l[e] = acc[e] + (double)br[e]; m = fmax(m, l[e]); }
    double s = 0.0;
#pragma unroll
    for (int e = 0; e < NEXP; e++) { p[e] = exp(l[e] - m); s += p[e]; }
    double inv = 1.0 / s;
#pragma unroll
    for (int e = 0; e < NEXP; e++) p[e] *= inv;
    int e0 = 0;
    for (int e = 1; e < NEXP; e++) if (p[e] > p[e0]) e0 = e;
    int e1 = -1;
    for (int e = 0; e < NEXP; e++) { if (e == e0) continue; if (e1 < 0 || p[e] > p[e1]) e1 = e; }

    int pos0 = atomicAdd(&counts[e0], 1);
    int pos1 = atomicAdd(&counts[e1], 1);
    atomicAdd(&cntse[0 * NEXP + e0], 1);
    atomicAdd(&cntse[1 * NEXP + e1], 1);
    eArr[n * 2 + 0] = e0;  eArr[n * 2 + 1] = e1;
    wArr[n * 2 + 0] = (float)p[e0];  wArr[n * 2 + 1] = (float)p[e1];
    posArr[n * 2 + 0] = pos0;  posArr[n * 2 + 1] = pos1;
  }
}

__global__ void k_prefix(char* ws) {
  int* counts = (int*)(ws + WS_COUNTS);
  int* cntse  = (int*)(ws + WS_CNTSE);
  int* offs   = (int*)(ws + WS_OFFS);
  int* incl   = (int*)(ws + WS_INCL);
  if (threadIdx.x == 0) {
    int o = 0;
    for (int e = 0; e < NEXP; e++) { offs[e] = o; o += counts[e]; }
    offs[NEXP] = o;
  }
  if (threadIdx.x < 16) incl[threadIdx.x] = (cntse[threadIdx.x] > 0) ? 1 : 0;
}

__global__ __launch_bounds__(256) void k_scatter(char* ws) {
  int* eArr   = (int*)(ws + WS_EARR);
  float* wArr = (float*)(ws + WS_WARR);
  int* posArr = (int*)(ws + WS_POS);
  int* offs   = (int*)(ws + WS_OFFS);
  int* ttok   = (int*)(ws + WS_TTOK);
  float* tw   = (float*)(ws + WS_TW);
  int n = blockIdx.x * 256 + threadIdx.x;
  if (n >= N_TOK) return;
#pragma unroll
  for (int s = 0; s < 2; s++) {
    int e = eArr[n * 2 + s];
    int t = offs[e] + posArr[n * 2 + s];
    ttok[t] = n;
    tw[t] = wArr[n * 2 + s];
  }
}

// ---------------- Sv[s] = sum of included c_e ----------------
__global__ __launch_bounds__(256) void k_sv(char* ws) {
  float* cbuf = (float*)(ws + WS_CBUF);
  float* sv   = (float*)(ws + WS_SV);
  int* incl   = (int*)(ws + WS_INCL);
  int i = blockIdx.x * 256 + threadIdx.x;
  int s = i >> 10, d = i & 1023;
  float acc = 0.f;
#pragma unroll
  for (int e = 0; e < NEXP; e++) if (incl[s * NEXP + e]) acc += cbuf[e * DIMX + d];
  sv[i] = acc;
}

// ================= FAST PATH =================

// x f32 -> bf16
__global__ __launch_bounds__(256) void k_cvtx(const float* __restrict__ x, char* ws) {
  ushortT* xb = (ushortT*)(ws + WS_XBF);
  size_t i = ((size_t)blockIdx.x * 256 + threadIdx.x) * 8;
  float4 a = *(const float4*)(x + i);
  float4 b = *(const float4*)(x + i + 4);
  short8 v;
  v[0] = (short)f2bf(a.x); v[1] = (short)f2bf(a.y);
  v[2] = (short)f2bf(a.z); v[3] = (short)f2bf(a.w);
  v[4] = (short)f2bf(b.x); v[5] = (short)f2bf(b.y);
  v[6] = (short)f2bf(b.z); v[7] = (short)f2bf(b.w);
  *(short8*)(xb + i) = v;
}

// transpose+convert: src f32 [e][R][C] -> dst bf16 [e][C][R]
__global__ __launch_bounds__(256) void k_tr(const float* __restrict__ src,
                                            ushortT* __restrict__ dst, int R, int C) {
  __shared__ __align__(16) ushortT Ls[64][72];
  int e = blockIdx.z;
  int r0 = blockIdx.y * 64, c0 = blockIdx.x * 64;
  int tid = threadIdx.x;
  int rr = tid >> 2, cc = (tid & 3) * 16;
  const float* s = src + ((size_t)e * R + r0 + rr) * C + c0 + cc;
  float4 v0 = *(const float4*)(s + 0);
  float4 v1 = *(const float4*)(s + 4);
  float4 v2 = *(const float4*)(s + 8);
  float4 v3 = *(const float4*)(s + 12);
  short8 p0, p1;
  p0[0]=(short)f2bf(v0.x); p0[1]=(short)f2bf(v0.y); p0[2]=(short)f2bf(v0.z); p0[3]=(short)f2bf(v0.w);
  p0[4]=(short)f2bf(v1.x); p0[5]=(short)f2bf(v1.y); p0[6]=(short)f2bf(v1.z); p0[7]=(short)f2bf(v1.w);
  p1[0]=(short)f2bf(v2.x); p1[1]=(short)f2bf(v2.y); p1[2]=(short)f2bf(v2.z); p1[3]=(short)f2bf(v2.w);
  p1[4]=(short)f2bf(v3.x); p1[5]=(short)f2bf(v3.y); p1[6]=(short)f2bf(v3.z); p1[7]=(short)f2bf(v3.w);
  *(short8*)&Ls[rr][cc] = p0;
  *(short8*)&Ls[rr][cc + 8] = p1;
  __syncthreads();
  int nn = tid >> 2;            // output row (col of tile)
  int kk = (tid & 3) * 16;      // output col base (row of tile)
  short8 o0, o1;
#pragma unroll
  for (int j = 0; j < 8; j++) o0[j] = (short)Ls[kk + j][nn];
#pragma unroll
  for (int j = 0; j < 8; j++) o1[j] = (short)Ls[kk + 8 + j][nn];
  ushortT* d = dst + ((size_t)e * C + c0 + nn) * R + r0 + kk;
  *(short8*)(d + 0) = o0;
  *(short8*)(d + 8) = o1;
}

// c_e[d] = sum_h relu(b1[e][h]) * W2t[e][d][h] + b2[e][d]
__global__ __launch_bounds__(256) void k_cvecn(const float* __restrict__ b1,
                                               const float* __restrict__ b2, char* ws) {
  const ushortT* w2t = (const ushortT*)(ws + WS_W2T);
  float* cbuf = (float*)(ws + WS_CBUF);
  int e = blockIdx.y;
  int lane = threadIdx.x & 63, w = threadIdx.x >> 6;
  int d = blockIdx.x * 4 + w;
  float acc = 0.f;
  const ushortT* wp = w2t + ((size_t)e * DIMX + d) * HID;
  const float* bp = b1 + (size_t)e * HID;
#pragma unroll
  for (int it = 0; it < 8; it++) {
    int h = it * 512 + lane * 8;
    short8 wv = *(const short8*)(wp + h);
    float4 ba = *(const float4*)(bp + h);
    float4 bb = *(const float4*)(bp + h + 4);
    acc += bf2f((ushortT)wv[0]) * fmaxf(ba.x, 0.f);
    acc += bf2f((ushortT)wv[1]) * fmaxf(ba.y, 0.f);
    acc += bf2f((ushortT)wv[2]) * fmaxf(ba.z, 0.f);
    acc += bf2f((ushortT)wv[3]) * fmaxf(ba.w, 0.f);
    acc += bf2f((ushortT)wv[4]) * fmaxf(bb.x, 0.f);
    acc += bf2f((ushortT)wv[5]) * fmaxf(bb.y, 0.f);
    acc += bf2f((ushortT)wv[6]) * fmaxf(bb.z, 0.f);
    acc += bf2f((ushortT)wv[7]) * fmaxf(bb.w, 0.f);
  }
  for (int o = 32; o > 0; o >>= 1) acc += __shfl_down(acc, o, 64);
  if (lane == 0) cbuf[e * DIMX + d] = acc + b2[(size_t)e * DIMX + d];
}

// GEMM1: g = relu(x@W1+b1) - relu(b1), bf16. 128x128 tile, BK=32 (m97 structure)
__global__ __launch_bounds__(256) void k_gemm1n(const float* __restrict__ b1, char* ws) {
  const int* offs = (const int*)(ws + WS_OFFS);
  const int* ttok = (const int*)(ws + WS_TTOK);
  const ushortT* xb  = (const ushortT*)(ws + WS_XBF);
  const ushortT* w1t = (const ushortT*)(ws + WS_W1T);
  ushortT* g = (ushortT*)(ws + WS_G);

  int e = blockIdx.z;
  int off = offs[e], cnt = offs[e + 1] - off;
  int m0 = blockIdx.x * 128;
  if (m0 >= cnt) return;
  int n0 = blockIdx.y * 128;

  __shared__ __align__(16) ushortT As[128][32];
  __shared__ __align__(16) ushortT Bs[128][32];

  int tid = threadIdx.x, lane = tid & 63, w = tid >> 6;
  int wm = w >> 1, wn = w & 1;
  int l4 = lane >> 2, c8 = (lane & 3) * 8;

  int ra0 = w * 32 + l4, ra1 = ra0 + 16;
  int mr0 = m0 + ra0, mr1 = m0 + ra1;
  int t0 = (mr0 < cnt) ? ttok[off + mr0] : 0;
  int t1 = (mr1 < cnt) ? ttok[off + mr1] : 0;
  const ushortT* pa0 = xb + (size_t)t0 * DIMX + c8;
  const ushortT* pa1 = xb + (size_t)t1 * DIMX + c8;
  const ushortT* pb0 = w1t + ((size_t)e * HID + n0 + ra0) * DIMX + c8;
  const ushortT* pb1 = pb0 + (size_t)16 * DIMX;
  char* lA = (char*)(&As[0][0]) + w * 2048;
  char* lB = (char*)(&Bs[0][0]) + w * 2048;

  f32x4 acc[4][4];
#pragma unroll
  for (int i = 0; i < 4; i++)
#pragma unroll
    for (int j = 0; j < 4; j++) acc[i][j] = (f32x4)0.f;

  int rsel = lane & 15, kg = lane >> 4;

  for (int ks = 0; ks < DIMX; ks += 32) {
    gl16(pa0 + ks, lA);
    gl16(pa1 + ks, lA + 1024);
    gl16(pb0 + ks, lB);
    gl16(pb1 + ks, lB + 1024);
    __syncthreads();
    short8 af[4], bf[4];
#pragma unroll
    for (int i = 0; i < 4; i++) af[i] = *(const short8*)&As[wm * 64 + i * 16 + rsel][kg * 8];
#pragma unroll
    for (int i = 0; i < 4; i++) bf[i] = *(const short8*)&Bs[wn * 64 + i * 16 + rsel][kg * 8];
#pragma unroll
    for (int i = 0; i < 4; i++)
#pragma unroll
      for (int j = 0; j < 4; j++)
        acc[i][j] = __builtin_amdgcn_mfma_f32_16x16x32_bf16(af[i], bf[j], acc[i][j], 0, 0, 0);
    __syncthreads();
  }

  int cr = (lane >> 4) * 4, ccol = lane & 15;
#pragma unroll
  for (int j = 0; j < 4; j++) {
    int col = n0 + wn * 64 + j * 16 + ccol;
    float b1v = b1[(size_t)e * HID + col];
    float rb = fmaxf(b1v, 0.f);
#pragma unroll
    for (int i = 0; i < 4; i++) {
      int mb = m0 + wm * 64 + i * 16 + cr;
#pragma unroll
      for (int r = 0; r < 4; r++) {
        int m = mb + r;
        if (m < cnt)
          g[(size_t)(off + m) * HID + col] = f2bf(fmaxf(acc[i][j][r] + b1v, 0.f) - rb);
      }
    }
  }
}

// GEMM2: y2[kh][task][d] = g[task][kh-half] @ W2t[e][d][kh-half]^T, f32. K split in 2.
__global__ __launch_bounds__(256) void k_gemm2n(char* ws) {
  const int* offs = (const int*)(ws + WS_OFFS);
  const ushortT* gq  = (const ushortT*)(ws + WS_G);
  const ushortT* w2t = (const ushortT*)(ws + WS_W2T);

  int z = blockIdx.z;
  int e = z >> 1, kh = z & 1;
  int off = offs[e], cnt = offs[e + 1] - off;
  int m0 = blockIdx.x * 128;
  if (m0 >= cnt) return;
  int n0 = blockIdx.y * 128;
  float* y2 = (float*)(ws + WS_Y2) + (size_t)kh * 4224 * DIMX;

  __shared__ __align__(16) ushortT As[128][32];
  __shared__ __align__(16) ushortT Bs[128][32];

  int tid = threadIdx.x, lane = tid & 63, w = tid >> 6;
  int wm = w >> 1, wn = w & 1;
  int l4 = lane >> 2, c8 = (lane & 3) * 8;

  int ra0 = w * 32 + l4, ra1 = ra0 + 16;
  const ushortT* pa0 = gq + (size_t)(off + m0 + ra0) * HID + kh * 2048 + c8;
  const ushortT* pa1 = gq + (size_t)(off + m0 + ra1) * HID + kh * 2048 + c8;
  const ushortT* pb0 = w2t + ((size_t)e * DIMX + n0 + ra0) * HID + kh * 2048 + c8;
  const ushortT* pb1 = pb0 + (size_t)16 * HID;
  char* lA = (char*)(&As[0][0]) + w * 2048;
  char* lB = (char*)(&Bs[0][0]) + w * 2048;

  f32x4 acc[4][4];
#pragma unroll
  for (int i = 0; i < 4; i++)
#pragma unroll
    for (int j = 0; j < 4; j++) acc[i][j] = (f32x4)0.f;

  int rsel = lane & 15, kg = lane >> 4;

  for (int ks = 0; ks < 2048; ks += 32) {
    gl16(pa0 + ks, lA);
    gl16(pa1 + ks, lA + 1024);
    gl16(pb0 + ks, lB);
    gl16(pb1 + ks, lB + 1024);
    __syncthreads();
    short8 af[4], bf[4];
#pragma unroll
    for (int i = 0; i < 4; i++) af[i] = *(const short8*)&As[wm * 64 + i * 16 + rsel][kg * 8];
#pragma unroll
    for (int i = 0; i < 4; i++) bf[i] = *(const short8*)&Bs[wn * 64 + i * 16 + rsel][kg * 8];
#pragma unroll
    for (int i = 0; i < 4; i++)
#pragma unroll
      for (int j = 0; j < 4; j++)
        acc[i][j] = __builtin_amdgcn_mfma_f32_16x16x32_bf16(af[i], bf[j], acc[i][j], 0, 0, 0);
    __syncthreads();
  }

  int cr = (lane >> 4) * 4, ccol = lane & 15;
#pragma unroll
  for (int i = 0; i < 4; i++) {
    int mb = m0 + wm * 64 + i * 16 + cr;
#pragma unroll
    for (int r = 0; r < 4; r++) {
      int m = mb + r;
      if (m < cnt) {
#pragma unroll
        for (int j = 0; j < 4; j++) {
          int col = n0 + wn * 64 + j * 16 + ccol;
          y2[(size_t)(off + m) * DIMX + col] = acc[i][j][r];
        }
      }
    }
  }
}

// out[n] = w0*(sv0 + y2a[t0] + y2b[t0]) + w1*(sv1 + y2a[t1] + y2b[t1])
__global__ __launch_bounds__(256) void k_final(char* ws, float* __restrict__ out) {
  const int* eArr   = (const int*)(ws + WS_EARR);
  const int* posArr = (const int*)(ws + WS_POS);
  const int* offs   = (const int*)(ws + WS_OFFS);
  const float* wArr = (const float*)(ws + WS_WARR);
  const float* sv   = (const float*)(ws + WS_SV);
  const float* y2   = (const float*)(ws + WS_Y2);

  int n = blockIdx.x;
  int e0 = eArr[2 * n], e1 = eArr[2 * n + 1];
  int t0 = offs[e0] + posArr[2 * n];
  int t1 = offs[e1] + posArr[2 * n + 1];
  float w0 = wArr[2 * n], w1 = wArr[2 * n + 1];
  const float* ya0 = y2 + (size_t)t0 * DIMX;
  const float* yb0 = y2 + ((size_t)4224 + t0) * DIMX;
  const float* ya1 = y2 + (size_t)t1 * DIMX;
  const float* yb1 = y2 + ((size_t)4224 + t1) * DIMX;

  int d = threadIdx.x * 4;
  float4 r0a = *(const float4*)(ya0 + d);
  float4 r0b = *(const float4*)(yb0 + d);
  float4 r1a = *(const float4*)(ya1 + d);
  float4 r1b = *(const float4*)(yb1 + d);
  float4 s0 = *(const float4*)(sv + d);
  float4 s1 = *(const float4*)(sv + DIMX + d);
  float4 o;
  o.x = w0 * (s0.x + r0a.x + r0b.x) + w1 * (s1.x + r1a.x + r1b.x);
  o.y = w0 * (s0.y + r0a.y + r0b.y) + w1 * (s1.y + r1a.y + r1b.y);
  o.z = w0 * (s0.z + r0a.z + r0b.z) + w1 * (s1.z + r1a.z + r1b.z);
  o.w = w0 * (s0.w + r0a.w + r0b.w) + w1 * (s1.w + r1a.w + r1b.w);
  *(float4*)(out + (size_t)n * DIMX + d) = o;
}

// ================= FALLBACK PATH (round-1, known-pass) =================

__global__ __launch_bounds__(256) void k_cvec_f(const float* __restrict__ W2,
                                                const float* __restrict__ b1,
                                                const float* __restrict__ b2,
                                                char* ws) {
  float* cbuf = (float*)(ws + WS_CBUF);
  int e = blockIdx.y;
  int d = blockIdx.x * 256 + threadIdx.x;
  int h0 = blockIdx.z * 512;
  __shared__ float rb[512];
  for (int h = threadIdx.x; h < 512; h += 256) rb[h] = fmaxf(b1[(size_t)e * HID + h0 + h], 0.f);
  __syncthreads();
  float acc = (blockIdx.z == 0) ? b2[(size_t)e * DIMX + d] : 0.f;
  const float* w = W2 + (size_t)e * HID * DIMX + (size_t)h0 * DIMX + d;
#pragma unroll 8
  for (int h = 0; h < 512; h++) acc += rb[h] * w[(size_t)h * DIMX];
  atomicAdd(&cbuf[e * DIMX + d], acc);
}

__global__ __launch_bounds__(256) void k_base_f(char* ws, float* __restrict__ out) {
  float* wArr = (float*)(ws + WS_WARR);
  float* sv   = (float*)(ws + WS_SV);
  int n = blockIdx.x;
  float w0 = wArr[n * 2], w1 = wArr[n * 2 + 1];
  for (int d = threadIdx.x; d < DIMX; d += 256)
    out[(size_t)n * DIMX + d] = w0 * sv[d] + w1 * sv[DIMX + d];
}

__global__ __launch_bounds__(256) void k_gemm1_f(const float* __restrict__ x,
                                                 const float* __restrict__ W1,
                                                 const float* __restrict__ b1,
                                                 char* ws) {
  int* offs = (int*)(ws + WS_OFFS);
  int* ttok = (int*)(ws + WS_TTOK);
  unsigned short* g = (unsigned short*)(ws + WS_G_F);

  int e = blockIdx.z;
  int off = offs[e];
  int cnt = offs[e + 1] - off;
  int m0 = blockIdx.x * 64;
  if (m0 >= cnt) return;
  int n0 = blockIdx.y * 64;

  __shared__ __align__(16) unsigned short As[64][40];
  __shared__ __align__(16) unsigned short Bs[64][40];

  int tid = threadIdx.x;
  int lane = tid & 63;
  int wid = tid >> 6;
  int wm = wid >> 1, wn = wid & 1;

  int ar = tid >> 2;
  int akc = (tid & 3) * 8;
  int arow = m0 + ar;
  int tok = (arow < cnt) ? ttok[off + arow] : 0;
  const float* aptr = x + (size_t)tok * DIMX;
  int bj = tid & 63;
  int bk = (tid >> 6) * 8;
  const float* bbase = W1 + (size_t)e * DIMX * HID + n0 + bj;

  f32x4 acc[2][2];
#pragma unroll
  for (int i = 0; i < 2; i++)
#pragma unroll
    for (int j = 0; j < 2; j++) acc[i][j] = (f32x4)0.f;

  int kg = (lane >> 4) * 8;
  int rsel = lane & 15;

  for (int ks = 0; ks < DIMX; ks += 32) {
    float4 a0 = *(const float4*)(aptr + ks + akc);
    float4 a1 = *(const float4*)(aptr + ks + akc + 4);
    short8 av;
    av[0] = (short)f2bf(a0.x); av[1] = (short)f2bf(a0.y);
    av[2] = (short)f2bf(a0.z); av[3] = (short)f2bf(a0.w);
    av[4] = (short)f2bf(a1.x); av[5] = (short)f2bf(a1.y);
    av[6] = (short)f2bf(a1.z); av[7] = (short)f2bf(a1.w);
    *(short8*)&As[ar][akc] = av;

    short8 bv;
#pragma unroll
    for (int i = 0; i < 8; i++)
      bv[i] = (short)f2bf(bbase[(size_t)(ks + bk + i) * HID]);
    *(short8*)&Bs[bj][bk] = bv;

    __syncthreads();
    short8 af0 = *(short8*)&As[wm * 32 + rsel][kg];
    short8 af1 = *(short8*)&As[wm * 32 + 16 + rsel][kg];
    short8 bf0 = *(short8*)&Bs[wn * 32 + rsel][kg];
    short8 bf1 = *(short8*)&Bs[wn * 32 + 16 + rsel][kg];
    acc[0][0] = __builtin_amdgcn_mfma_f32_16x16x32_bf16(af0, bf0, acc[0][0], 0, 0, 0);
    acc[0][1] = __builtin_amdgcn_mfma_f32_16x16x32_bf16(af0, bf1, acc[0][1], 0, 0, 0);
    acc[1][0] = __builtin_amdgcn_mfma_f32_16x16x32_bf16(af1, bf0, acc[1][0], 0, 0, 0);
    acc[1][1] = __builtin_amdgcn_mfma_f32_16x16x32_bf16(af1, bf1, acc[1][1], 0, 0, 0);
    __syncthreads();
  }

  int crow = (lane >> 4) * 4;
  int ccol = lane & 15;
#pragma unroll
  for (int fn = 0; fn < 2; fn++) {
    int j = n0 + wn * 32 + fn * 16 + ccol;
    float b1v = b1[(size_t)e * HID + j];
    float rb = fmaxf(b1v, 0.f);
#pragma unroll
    for (int fm = 0; fm < 2; fm++) {
#pragma unroll
      for (int r = 0; r < 4; r++) {
        int m = m0 + wm * 32 + fm * 16 + crow + r;
        if (m < cnt) {
          float v = fmaxf(acc[fm][fn][r] + b1v, 0.f) - rb;
          g[(size_t)(off + m) * HID + j] = f2bf(v);
        }
      }
    }
  }
}

__global__ __launch_bounds__(256) void k_gemm2_f(const float* __restrict__ W2,
                                                 char* ws, float* __restrict__ out) {
  int* offs = (int*)(ws + WS_OFFS);
  int* ttok = (int*)(ws + WS_TTOK);
  float* tw = (float*)(ws + WS_TW);
  const unsigned short* g = (const unsigned short*)(ws + WS_G_F);

  int e = blockIdx.z;
  int off = offs[e];
  int cnt = offs[e + 1] - off;
  int m0 = blockIdx.x * 64;
  if (m0 >= cnt) return;
  int n0 = blockIdx.y * 64;

  __shared__ __align__(16) unsigned short As[64][40];
  __shared__ __align__(16) unsigned short Bs[64][40];

  int tid = threadIdx.x;
  int lane = tid & 63;
  int wid = tid >> 6;
  int wm = wid >> 1, wn = wid & 1;

  int ar = tid >> 2;
  int akc = (tid & 3) * 8;
  const unsigned short* aptr = g + (size_t)(off + m0 + ar) * HID;
  int bj = tid & 63;
  int bk = (tid >> 6) * 8;
  const float* bbase = W2 + (size_t)e * HID * DIMX + n0 + bj;

  f32x4 acc[2][2];
#pragma unroll
  for (int i = 0; i < 2; i++)
#pragma unroll
    for (int j = 0; j < 2; j++) acc[i][j] = (f32x4)0.f;

  int kg = (lane >> 4) * 8;
  int rsel = lane & 15;

  for (int ks = 0; ks < HID; ks += 32) {
    short8 av = *(const short8*)(aptr + ks + akc);
    *(short8*)&As[ar][akc] = av;
    short8 bv;
#pragma unroll
    for (int i = 0; i < 8; i++)
      bv[i] = (short)f2bf(bbase[(size_t)(ks + bk + i) * DIMX]);
    *(short8*)&Bs[bj][bk] = bv;

    __syncthreads();
    short8 af0 = *(short8*)&As[wm * 32 + rsel][kg];
    short8 af1 = *(short8*)&As[wm * 32 + 16 + rsel][kg];
    short8 bf0 = *(short8*)&Bs[wn * 32 + rsel][kg];
    short8 bf1 = *(short8*)&Bs[wn * 32 + 16 + rsel][kg];
    acc[0][0] = __builtin_amdgcn_mfma_f32_16x16x32_bf16(af0, bf0, acc[0][0], 0, 0, 0);
    acc[0][1] = __builtin_amdgcn_mfma_f32_16x16x32_bf16(af0, bf1, acc[0][1], 0, 0, 0);
    acc[1][0] = __builtin_amdgcn_mfma_f32_16x16x32_bf16(af1, bf0, acc[1][0], 0, 0, 0);
    acc[1][1] = __builtin_amdgcn_mfma_f32_16x16x32_bf16(af1, bf1, acc[1][1], 0, 0, 0);
    __syncthreads();
  }

  int crow = (lane >> 4) * 4;
  int ccol = lane & 15;
#pragma unroll
  for (int fm = 0; fm < 2; fm++) {
#pragma unroll
    for (int r = 0; r < 4; r++) {
      int m = m0 + wm * 32 + fm * 16 + crow + r;
      if (m < cnt) {
        int tok = ttok[off + m];
        float w = tw[off + m];
#pragma unroll
        for (int fn = 0; fn < 2; fn++) {
          int j = n0 + wn * 32 + fn * 16 + ccol;
          atomicAdd(&out[(size_t)tok * DIMX + j], w * acc[fm][fn][r]);
        }
      }
    }
  }
}

extern "C" void kernel_launch(void* const* d_in, const int* in_sizes, int n_in,
                              void* d_out, int out_size, void* d_ws, size_t ws_size,
                              hipStream_t stream) {
  const float* x  = (const float*)d_in[0];
  const float* Wr = (const float*)d_in[1];
  const float* br = (const float*)d_in[2];
  const float* W1 = (const float*)d_in[3];
  const float* b1 = (const float*)d_in[4];
  const float* W2 = (const float*)d_in[5];
  const float* b2 = (const float*)d_in[6];
  float* out = (float*)d_out;
  char* ws = (char*)d_ws;

  bool fast = ws_size >= WS_NEED;

  hipMemsetAsync(ws, 0, WS_ZERO_BYTES, stream);
  k_router<<<N_TOK / 4, 256, 0, stream>>>(x, Wr, br, ws);
  k_prefix<<<1, 64, 0, stream>>>(ws);
  k_scatter<<<N_TOK / 256, 256, 0, stream>>>(ws);

  if (fast) {
    k_cvtx<<<1024, 256, 0, stream>>>(x, ws);
    k_tr<<<dim3(64, 16, 8), 256, 0, stream>>>(W1, (ushortT*)(ws + WS_W1T), DIMX, HID);
    k_tr<<<dim3(16, 64, 8), 256, 0, stream>>>(W2, (ushortT*)(ws + WS_W2T), HID, DIMX);
    k_cvecn<<<dim3(256, 8), 256, 0, stream>>>(b1, b2, ws);
    k_sv<<<8, 256, 0, stream>>>(ws);
    k_gemm1n<<<dim3(32, 32, 8), 256, 0, stream>>>(b1, ws);
    k_gemm2n<<<dim3(32, 8, 16), 256, 0, stream>>>(ws);
    k_final<<<N_TOK, 256, 0, stream>>>(ws, out);
  } else {
    k_cvec_f<<<dim3(4, NEXP, 8), 256, 0, stream>>>(W2, b1, b2, ws);
    k_sv<<<8, 256, 0, stream>>>(ws);
    k_base_f<<<N_TOK, 256, 0, stream>>>(ws, out);
    k_gemm1_f<<<dim3(32, HID / 64, NEXP), 256, 0, stream>>>(x, W1, b1, ws);
    k_gemm2_f<<<dim3(32, DIMX / 64, NEXP), 256, 0, stream>>>(W2, ws, out);
  }
}

// Round 6
// 818.062 us; speedup vs baseline: 1.4191x; 1.3594x over previous
//
#include <hip/hip_runtime.h>
#include <hip/hip_bf16.h>
#include <math.h>

#define N_TOK 2048
#define DIMX  1024
#define NEXP  8
#define HID   4096

typedef __attribute__((ext_vector_type(8))) short short8;
typedef __attribute__((ext_vector_type(4))) float f32x4;
typedef unsigned short ushortT;

__device__ __forceinline__ unsigned short f2bf(float f) {
  unsigned int u = __float_as_uint(f);
  u += 0x7fff + ((u >> 16) & 1);   // RTNE
  return (unsigned short)(u >> 16);
}
__device__ __forceinline__ float bf2f(unsigned short u) {
  return __uint_as_float(((unsigned)u) << 16);
}
__device__ __forceinline__ void gl16(const void* g, void* l) {
  __builtin_amdgcn_global_load_lds((const __attribute__((address_space(1))) unsigned*)g,
                                   (__attribute__((address_space(3))) unsigned*)l, 16, 0, 0);
}

// ---------------- ws layout (bytes) ----------------
#define WS_COUNTS   0        // 8  i32  (zeroed)
#define WS_CNTSE    64       // 16 i32  (zeroed)
#define WS_OFFS     192      // 9  i32
#define WS_INCL     256      // 16 i32
#define WS_CBUF     1024     // 8*1024 f32
#define WS_SV       33792    // 2*1024 f32
#define WS_EARR     49152    // 2048*2 i32
#define WS_WARR     65536    // 2048*2 f32
#define WS_POS      81920    // 2048*2 i32
#define WS_TTOK     98304    // 4096 i32
#define WS_TW       114688   // 4096 f32
#define WS_G_F      131072   // fallback g: (4096+64)*4096 bf16
// fast-path buffers
#define WS_XBF      4194304ull                     // 2048*1024 bf16 = 4 MB
#define WS_W1T      8388608ull                     // 8*4096*1024 bf16 = 64 MB
#define WS_W2T      75497472ull                    // 8*1024*4096 bf16 = 64 MB
#define WS_G        142606336ull                   // 4224*4096 bf16 = 34.6 MB
#define WS_NEED     211812352ull
#define WS_ZERO_BYTES 33792

// ---------------- router (f64 for selection robustness) ----------------
__global__ __launch_bounds__(256) void k_router(const float* __restrict__ x,
                                                const float* __restrict__ Wr,
                                                const float* __restrict__ br,
                                                char* ws) {
  int* counts = (int*)(ws + WS_COUNTS);
  int* cntse  = (int*)(ws + WS_CNTSE);
  int* eArr   = (int*)(ws + WS_EARR);
  float* wArr = (float*)(ws + WS_WARR);
  int* posArr = (int*)(ws + WS_POS);

  int wid  = threadIdx.x >> 6;
  int lane = threadIdx.x & 63;
  int n = blockIdx.x * 4 + wid;

  double acc[NEXP];
#pragma unroll
  for (int e = 0; e < NEXP; e++) acc[e] = 0.0;
  const float* xr = x + (size_t)n * DIMX;
  for (int i = 0; i < DIMX / 64; i++) {
    int kk = i * 64 + lane;
    double xv = (double)xr[kk];
    const float* wr = Wr + (size_t)kk * NEXP;
#pragma unroll
    for (int e = 0; e < NEXP; e++) acc[e] += xv * (double)wr[e];
  }
#pragma unroll
  for (int e = 0; e < NEXP; e++) {
    for (int off = 32; off > 0; off >>= 1)
      acc[e] += __shfl_down(acc[e], off, 64);
  }
  if (lane == 0) {
    double l[NEXP], p[NEXP];
    double m = -1e300;
#pragma unroll
    for (int e = 0; e < NEXP; e++) { l[e] = acc[e] + (double)br[e]; m = fmax(m, l[e]); }
    double s = 0.0;
#pragma unroll
    for (int e = 0; e < NEXP; e++) { p[e] = exp(l[e] - m); s += p[e]; }
    double inv = 1.0 / s;
#pragma unroll
    for (int e = 0; e < NEXP; e++) p[e] *= inv;
    int e0 = 0;
    for (int e = 1; e < NEXP; e++) if (p[e] > p[e0]) e0 = e;
    int e1 = -1;
    for (int e = 0; e < NEXP; e++) { if (e == e0) continue; if (e1 < 0 || p[e] > p[e1]) e1 = e; }

    int pos0 = atomicAdd(&counts[e0], 1);
    int pos1 = atomicAdd(&counts[e1], 1);
    atomicAdd(&cntse[0 * NEXP + e0], 1);
    atomicAdd(&cntse[1 * NEXP + e1], 1);
    eArr[n * 2 + 0] = e0;  eArr[n * 2 + 1] = e1;
    wArr[n * 2 + 0] = (float)p[e0];  wArr[n * 2 + 1] = (float)p[e1];
    posArr[n * 2 + 0] = pos0;  posArr[n * 2 + 1] = pos1;
  }
}

__global__ void k_prefix(char* ws) {
  int* counts = (int*)(ws + WS_COUNTS);
  int* cntse  = (int*)(ws + WS_CNTSE);
  int* offs   = (int*)(ws + WS_OFFS);
  int* incl   = (int*)(ws + WS_INCL);
  if (threadIdx.x == 0) {
    int o = 0;
    for (int e = 0; e < NEXP; e++) { offs[e] = o; o += counts[e]; }
    offs[NEXP] = o;
  }
  if (threadIdx.x < 16) incl[threadIdx.x] = (cntse[threadIdx.x] > 0) ? 1 : 0;
}

__global__ __launch_bounds__(256) void k_scatter(char* ws) {
  int* eArr   = (int*)(ws + WS_EARR);
  float* wArr = (float*)(ws + WS_WARR);
  int* posArr = (int*)(ws + WS_POS);
  int* offs   = (int*)(ws + WS_OFFS);
  int* ttok   = (int*)(ws + WS_TTOK);
  float* tw   = (float*)(ws + WS_TW);
  int n = blockIdx.x * 256 + threadIdx.x;
  if (n >= N_TOK) return;
#pragma unroll
  for (int s = 0; s < 2; s++) {
    int e = eArr[n * 2 + s];
    int t = offs[e] + posArr[n * 2 + s];
    ttok[t] = n;
    tw[t] = wArr[n * 2 + s];
  }
}

// ---------------- Sv[s] = sum of included c_e ----------------
__global__ __launch_bounds__(256) void k_sv(char* ws) {
  float* cbuf = (float*)(ws + WS_CBUF);
  float* sv   = (float*)(ws + WS_SV);
  int* incl   = (int*)(ws + WS_INCL);
  int i = blockIdx.x * 256 + threadIdx.x;
  int s = i >> 10, d = i & 1023;
  float acc = 0.f;
#pragma unroll
  for (int e = 0; e < NEXP; e++) if (incl[s * NEXP + e]) acc += cbuf[e * DIMX + d];
  sv[i] = acc;
}

// out[n] = w0*sv0 + w1*sv1  (baseline; GEMM2 atomically adds the rest)
__global__ __launch_bounds__(256) void k_base(char* ws, float* __restrict__ out) {
  float* wArr = (float*)(ws + WS_WARR);
  float* sv   = (float*)(ws + WS_SV);
  int n = blockIdx.x;
  float w0 = wArr[n * 2], w1 = wArr[n * 2 + 1];
  int d = threadIdx.x * 4;
  float4 s0 = *(const float4*)(sv + d);
  float4 s1 = *(const float4*)(sv + DIMX + d);
  float4 o;
  o.x = w0 * s0.x + w1 * s1.x;
  o.y = w0 * s0.y + w1 * s1.y;
  o.z = w0 * s0.z + w1 * s1.z;
  o.w = w0 * s0.w + w1 * s1.w;
  *(float4*)(out + (size_t)n * DIMX + d) = o;
}

// ================= FAST PATH =================

__global__ __launch_bounds__(256) void k_cvtx(const float* __restrict__ x, char* ws) {
  ushortT* xb = (ushortT*)(ws + WS_XBF);
  size_t i = ((size_t)blockIdx.x * 256 + threadIdx.x) * 8;
  float4 a = *(const float4*)(x + i);
  float4 b = *(const float4*)(x + i + 4);
  short8 v;
  v[0] = (short)f2bf(a.x); v[1] = (short)f2bf(a.y);
  v[2] = (short)f2bf(a.z); v[3] = (short)f2bf(a.w);
  v[4] = (short)f2bf(b.x); v[5] = (short)f2bf(b.y);
  v[6] = (short)f2bf(b.z); v[7] = (short)f2bf(b.w);
  *(short8*)(xb + i) = v;
}

// transpose+convert: src f32 [e][R][C] -> dst bf16 [e][C][R]
__global__ __launch_bounds__(256) void k_tr(const float* __restrict__ src,
                                            ushortT* __restrict__ dst, int R, int C) {
  __shared__ __align__(16) ushortT Ls[64][72];
  int e = blockIdx.z;
  int r0 = blockIdx.y * 64, c0 = blockIdx.x * 64;
  int tid = threadIdx.x;
  int rr = tid >> 2, cc = (tid & 3) * 16;
  const float* s = src + ((size_t)e * R + r0 + rr) * C + c0 + cc;
  float4 v0 = *(const float4*)(s + 0);
  float4 v1 = *(const float4*)(s + 4);
  float4 v2 = *(const float4*)(s + 8);
  float4 v3 = *(const float4*)(s + 12);
  short8 p0, p1;
  p0[0]=(short)f2bf(v0.x); p0[1]=(short)f2bf(v0.y); p0[2]=(short)f2bf(v0.z); p0[3]=(short)f2bf(v0.w);
  p0[4]=(short)f2bf(v1.x); p0[5]=(short)f2bf(v1.y); p0[6]=(short)f2bf(v1.z); p0[7]=(short)f2bf(v1.w);
  p1[0]=(short)f2bf(v2.x); p1[1]=(short)f2bf(v2.y); p1[2]=(short)f2bf(v2.z); p1[3]=(short)f2bf(v2.w);
  p1[4]=(short)f2bf(v3.x); p1[5]=(short)f2bf(v3.y); p1[6]=(short)f2bf(v3.z); p1[7]=(short)f2bf(v3.w);
  *(short8*)&Ls[rr][cc] = p0;
  *(short8*)&Ls[rr][cc + 8] = p1;
  __syncthreads();
  int nn = tid >> 2;
  int kk = (tid & 3) * 16;
  short8 o0, o1;
#pragma unroll
  for (int j = 0; j < 8; j++) o0[j] = (short)Ls[kk + j][nn];
#pragma unroll
  for (int j = 0; j < 8; j++) o1[j] = (short)Ls[kk + 8 + j][nn];
  ushortT* d = dst + ((size_t)e * C + c0 + nn) * R + r0 + kk;
  *(short8*)(d + 0) = o0;
  *(short8*)(d + 8) = o1;
}

// c_e[d] = sum_h relu(b1[e][h]) * W2t[e][d][h] + b2[e][d]
__global__ __launch_bounds__(256) void k_cvecn(const float* __restrict__ b1,
                                               const float* __restrict__ b2, char* ws) {
  const ushortT* w2t = (const ushortT*)(ws + WS_W2T);
  float* cbuf = (float*)(ws + WS_CBUF);
  int e = blockIdx.y;
  int lane = threadIdx.x & 63, w = threadIdx.x >> 6;
  int d = blockIdx.x * 4 + w;
  float acc = 0.f;
  const ushortT* wp = w2t + ((size_t)e * DIMX + d) * HID;
  const float* bp = b1 + (size_t)e * HID;
#pragma unroll
  for (int it = 0; it < 8; it++) {
    int h = it * 512 + lane * 8;
    short8 wv = *(const short8*)(wp + h);
    float4 ba = *(const float4*)(bp + h);
    float4 bb = *(const float4*)(bp + h + 4);
    acc += bf2f((ushortT)wv[0]) * fmaxf(ba.x, 0.f);
    acc += bf2f((ushortT)wv[1]) * fmaxf(ba.y, 0.f);
    acc += bf2f((ushortT)wv[2]) * fmaxf(ba.z, 0.f);
    acc += bf2f((ushortT)wv[3]) * fmaxf(ba.w, 0.f);
    acc += bf2f((ushortT)wv[4]) * fmaxf(bb.x, 0.f);
    acc += bf2f((ushortT)wv[5]) * fmaxf(bb.y, 0.f);
    acc += bf2f((ushortT)wv[6]) * fmaxf(bb.z, 0.f);
    acc += bf2f((ushortT)wv[7]) * fmaxf(bb.w, 0.f);
  }
  for (int o = 32; o > 0; o >>= 1) acc += __shfl_down(acc, o, 64);
  if (lane == 0) cbuf[e * DIMX + d] = acc + b2[(size_t)e * DIMX + d];
}

// GEMM1: g = relu(x@W1+b1) - relu(b1), bf16. 128x128, BK=32, double-buffered 2-phase.
__global__ __launch_bounds__(256) void k_gemm1n(const float* __restrict__ b1, char* ws) {
  const int* offs = (const int*)(ws + WS_OFFS);
  const int* ttok = (const int*)(ws + WS_TTOK);
  const ushortT* xb  = (const ushortT*)(ws + WS_XBF);
  const ushortT* w1t = (const ushortT*)(ws + WS_W1T);
  ushortT* g = (ushortT*)(ws + WS_G);

  int e = blockIdx.z;
  int off = offs[e], cnt = offs[e + 1] - off;
  int m0 = blockIdx.x * 128;
  if (m0 >= cnt) return;
  int n0 = blockIdx.y * 128;

  __shared__ __align__(16) ushortT As[2][128][32];
  __shared__ __align__(16) ushortT Bs[2][128][32];

  int tid = threadIdx.x, lane = tid & 63, w = tid >> 6;
  int wm = w >> 1, wn = w & 1;
  int l4 = lane >> 2, c8 = (lane & 3) * 8;

  int ra0 = w * 32 + l4, ra1 = ra0 + 16;
  int mr0 = m0 + ra0, mr1 = m0 + ra1;
  int t0 = (mr0 < cnt) ? ttok[off + mr0] : 0;
  int t1 = (mr1 < cnt) ? ttok[off + mr1] : 0;
  const ushortT* pa0 = xb + (size_t)t0 * DIMX + c8;
  const ushortT* pa1 = xb + (size_t)t1 * DIMX + c8;
  const ushortT* pb0 = w1t + ((size_t)e * HID + n0 + ra0) * DIMX + c8;
  const ushortT* pb1 = pb0 + (size_t)16 * DIMX;
  char* lA = (char*)(&As[0][0][0]) + w * 2048;   // +8192 per buffer
  char* lB = (char*)(&Bs[0][0][0]) + w * 2048;

#define STG1(buf, ks)                                  \
  {                                                    \
    gl16(pa0 + (ks), lA + (buf) * 8192);               \
    gl16(pa1 + (ks), lA + (buf) * 8192 + 1024);        \
    gl16(pb0 + (ks), lB + (buf) * 8192);               \
    gl16(pb1 + (ks), lB + (buf) * 8192 + 1024);        \
  }

  f32x4 acc[4][4];
#pragma unroll
  for (int i = 0; i < 4; i++)
#pragma unroll
    for (int j = 0; j < 4; j++) acc[i][j] = (f32x4)0.f;

  int rsel = lane & 15, kg = lane >> 4;

  STG1(0, 0);
  __syncthreads();
  int cur = 0;
  for (int it = 0; it < DIMX / 32; ++it) {
    if (it < DIMX / 32 - 1) STG1(cur ^ 1, (it + 1) * 32);
    short8 af[4], bf[4];
#pragma unroll
    for (int i = 0; i < 4; i++) af[i] = *(const short8*)&As[cur][wm * 64 + i * 16 + rsel][kg * 8];
#pragma unroll
    for (int i = 0; i < 4; i++) bf[i] = *(const short8*)&Bs[cur][wn * 64 + i * 16 + rsel][kg * 8];
#pragma unroll
    for (int i = 0; i < 4; i++)
#pragma unroll
      for (int j = 0; j < 4; j++)
        acc[i][j] = __builtin_amdgcn_mfma_f32_16x16x32_bf16(af[i], bf[j], acc[i][j], 0, 0, 0);
    __syncthreads();
    cur ^= 1;
  }
#undef STG1

  int cr = (lane >> 4) * 4, ccol = lane & 15;
#pragma unroll
  for (int j = 0; j < 4; j++) {
    int col = n0 + wn * 64 + j * 16 + ccol;
    float b1v = b1[(size_t)e * HID + col];
    float rb = fmaxf(b1v, 0.f);
#pragma unroll
    for (int i = 0; i < 4; i++) {
      int mb = m0 + wm * 64 + i * 16 + cr;
#pragma unroll
      for (int r = 0; r < 4; r++) {
        int m = mb + r;
        if (m < cnt)
          g[(size_t)(off + m) * HID + col] = f2bf(fmaxf(acc[i][j][r] + b1v, 0.f) - rb);
      }
    }
  }
}

// GEMM2: out[tok] += w * (g @ W2t^T). K split 4 (z = e*4+kh), dbuf 2-phase, atomic f32 epilogue.
__global__ __launch_bounds__(256) void k_gemm2n(char* ws, float* __restrict__ out) {
  const int* offs = (const int*)(ws + WS_OFFS);
  const int* ttok = (const int*)(ws + WS_TTOK);
  const float* tw = (const float*)(ws + WS_TW);
  const ushortT* gq  = (const ushortT*)(ws + WS_G);
  const ushortT* w2t = (const ushortT*)(ws + WS_W2T);

  int z = blockIdx.z;
  int e = z >> 2, kh = z & 3;          // K-chunk = 1024
  int off = offs[e], cnt = offs[e + 1] - off;
  int m0 = blockIdx.x * 128;
  if (m0 >= cnt) return;
  int n0 = blockIdx.y * 128;

  __shared__ __align__(16) ushortT As[2][128][32];
  __shared__ __align__(16) ushortT Bs[2][128][32];

  int tid = threadIdx.x, lane = tid & 63, w = tid >> 6;
  int wm = w >> 1, wn = w & 1;
  int l4 = lane >> 2, c8 = (lane & 3) * 8;

  int ra0 = w * 32 + l4, ra1 = ra0 + 16;
  const ushortT* pa0 = gq + (size_t)(off + m0 + ra0) * HID + kh * 1024 + c8;
  const ushortT* pa1 = gq + (size_t)(off + m0 + ra1) * HID + kh * 1024 + c8;
  const ushortT* pb0 = w2t + ((size_t)e * DIMX + n0 + ra0) * HID + kh * 1024 + c8;
  const ushortT* pb1 = pb0 + (size_t)16 * HID;
  char* lA = (char*)(&As[0][0][0]) + w * 2048;
  char* lB = (char*)(&Bs[0][0][0]) + w * 2048;

#define STG2(buf, ks)                                  \
  {                                                    \
    gl16(pa0 + (ks), lA + (buf) * 8192);               \
    gl16(pa1 + (ks), lA + (buf) * 8192 + 1024);        \
    gl16(pb0 + (ks), lB + (buf) * 8192);               \
    gl16(pb1 + (ks), lB + (buf) * 8192 + 1024);        \
  }

  f32x4 acc[4][4];
#pragma unroll
  for (int i = 0; i < 4; i++)
#pragma unroll
    for (int j = 0; j < 4; j++) acc[i][j] = (f32x4)0.f;

  int rsel = lane & 15, kg = lane >> 4;

  STG2(0, 0);
  __syncthreads();
  int cur = 0;
  for (int it = 0; it < 1024 / 32; ++it) {
    if (it < 1024 / 32 - 1) STG2(cur ^ 1, (it + 1) * 32);
    short8 af[4], bf[4];
#pragma unroll
    for (int i = 0; i < 4; i++) af[i] = *(const short8*)&As[cur][wm * 64 + i * 16 + rsel][kg * 8];
#pragma unroll
    for (int i = 0; i < 4; i++) bf[i] = *(const short8*)&Bs[cur][wn * 64 + i * 16 + rsel][kg * 8];
#pragma unroll
    for (int i = 0; i < 4; i++)
#pragma unroll
      for (int j = 0; j < 4; j++)
        acc[i][j] = __builtin_amdgcn_mfma_f32_16x16x32_bf16(af[i], bf[j], acc[i][j], 0, 0, 0);
    __syncthreads();
    cur ^= 1;
  }
#undef STG2

  int cr = (lane >> 4) * 4, ccol = lane & 15;
#pragma unroll
  for (int i = 0; i < 4; i++) {
    int mb = m0 + wm * 64 + i * 16 + cr;
#pragma unroll
    for (int r = 0; r < 4; r++) {
      int m = mb + r;
      if (m < cnt) {
        int tok = ttok[off + m];
        float wgt = tw[off + m];
#pragma unroll
        for (int j = 0; j < 4; j++) {
          int col = n0 + wn * 64 + j * 16 + ccol;
          atomicAdd(&out[(size_t)tok * DIMX + col], wgt * acc[i][j][r]);
        }
      }
    }
  }
}

// ================= FALLBACK PATH (round-1, known-pass) =================

__global__ __launch_bounds__(256) void k_cvec_f(const float* __restrict__ W2,
                                                const float* __restrict__ b1,
                                                const float* __restrict__ b2,
                                                char* ws) {
  float* cbuf = (float*)(ws + WS_CBUF);
  int e = blockIdx.y;
  int d = blockIdx.x * 256 + threadIdx.x;
  int h0 = blockIdx.z * 512;
  __shared__ float rb[512];
  for (int h = threadIdx.x; h < 512; h += 256) rb[h] = fmaxf(b1[(size_t)e * HID + h0 + h], 0.f);
  __syncthreads();
  float acc = (blockIdx.z == 0) ? b2[(size_t)e * DIMX + d] : 0.f;
  const float* w = W2 + (size_t)e * HID * DIMX + (size_t)h0 * DIMX + d;
#pragma unroll 8
  for (int h = 0; h < 512; h++) acc += rb[h] * w[(size_t)h * DIMX];
  atomicAdd(&cbuf[e * DIMX + d], acc);
}

__global__ __launch_bounds__(256) void k_gemm1_f(const float* __restrict__ x,
                                                 const float* __restrict__ W1,
                                                 const float* __restrict__ b1,
                                                 char* ws) {
  int* offs = (int*)(ws + WS_OFFS);
  int* ttok = (int*)(ws + WS_TTOK);
  unsigned short* g = (unsigned short*)(ws + WS_G_F);

  int e = blockIdx.z;
  int off = offs[e];
  int cnt = offs[e + 1] - off;
  int m0 = blockIdx.x * 64;
  if (m0 >= cnt) return;
  int n0 = blockIdx.y * 64;

  __shared__ __align__(16) unsigned short As[64][40];
  __shared__ __align__(16) unsigned short Bs[64][40];

  int tid = threadIdx.x;
  int lane = tid & 63;
  int wid = tid >> 6;
  int wm = wid >> 1, wn = wid & 1;

  int ar = tid >> 2;
  int akc = (tid & 3) * 8;
  int arow = m0 + ar;
  int tok = (arow < cnt) ? ttok[off + arow] : 0;
  const float* aptr = x + (size_t)tok * DIMX;
  int bj = tid & 63;
  int bk = (tid >> 6) * 8;
  const float* bbase = W1 + (size_t)e * DIMX * HID + n0 + bj;

  f32x4 acc[2][2];
#pragma unroll
  for (int i = 0; i < 2; i++)
#pragma unroll
    for (int j = 0; j < 2; j++) acc[i][j] = (f32x4)0.f;

  int kg = (lane >> 4) * 8;
  int rsel = lane & 15;

  for (int ks = 0; ks < DIMX; ks += 32) {
    float4 a0 = *(const float4*)(aptr + ks + akc);
    float4 a1 = *(const float4*)(aptr + ks + akc + 4);
    short8 av;
    av[0] = (short)f2bf(a0.x); av[1] = (short)f2bf(a0.y);
    av[2] = (short)f2bf(a0.z); av[3] = (short)f2bf(a0.w);
    av[4] = (short)f2bf(a1.x); av[5] = (short)f2bf(a1.y);
    av[6] = (short)f2bf(a1.z); av[7] = (short)f2bf(a1.w);
    *(short8*)&As[ar][akc] = av;

    short8 bv;
#pragma unroll
    for (int i = 0; i < 8; i++)
      bv[i] = (short)f2bf(bbase[(size_t)(ks + bk + i) * HID]);
    *(short8*)&Bs[bj][bk] = bv;

    __syncthreads();
    short8 af0 = *(short8*)&As[wm * 32 + rsel][kg];
    short8 af1 = *(short8*)&As[wm * 32 + 16 + rsel][kg];
    short8 bf0 = *(short8*)&Bs[wn * 32 + rsel][kg];
    short8 bf1 = *(short8*)&Bs[wn * 32 + 16 + rsel][kg];
    acc[0][0] = __builtin_amdgcn_mfma_f32_16x16x32_bf16(af0, bf0, acc[0][0], 0, 0, 0);
    acc[0][1] = __builtin_amdgcn_mfma_f32_16x16x32_bf16(af0, bf1, acc[0][1], 0, 0, 0);
    acc[1][0] = __builtin_amdgcn_mfma_f32_16x16x32_bf16(af1, bf0, acc[1][0], 0, 0, 0);
    acc[1][1] = __builtin_amdgcn_mfma_f32_16x16x32_bf16(af1, bf1, acc[1][1], 0, 0, 0);
    __syncthreads();
  }

  int crow = (lane >> 4) * 4;
  int ccol = lane & 15;
#pragma unroll
  for (int fn = 0; fn < 2; fn++) {
    int j = n0 + wn * 32 + fn * 16 + ccol;
    float b1v = b1[(size_t)e * HID + j];
    float rb = fmaxf(b1v, 0.f);
#pragma unroll
    for (int fm = 0; fm < 2; fm++) {
#pragma unroll
      for (int r = 0; r < 4; r++) {
        int m = m0 + wm * 32 + fm * 16 + crow + r;
        if (m < cnt) {
          float v = fmaxf(acc[fm][fn][r] + b1v, 0.f) - rb;
          g[(size_t)(off + m) * HID + j] = f2bf(v);
        }
      }
    }
  }
}

__global__ __launch_bounds__(256) void k_gemm2_f(const float* __restrict__ W2,
                                                 char* ws, float* __restrict__ out) {
  int* offs = (int*)(ws + WS_OFFS);
  int* ttok = (int*)(ws + WS_TTOK);
  float* tw = (float*)(ws + WS_TW);
  const unsigned short* g = (const unsigned short*)(ws + WS_G_F);

  int e = blockIdx.z;
  int off = offs[e];
  int cnt = offs[e + 1] - off;
  int m0 = blockIdx.x * 64;
  if (m0 >= cnt) return;
  int n0 = blockIdx.y * 64;

  __shared__ __align__(16) unsigned short As[64][40];
  __shared__ __align__(16) unsigned short Bs[64][40];

  int tid = threadIdx.x;
  int lane = tid & 63;
  int wid = tid >> 6;
  int wm = wid >> 1, wn = wid & 1;

  int ar = tid >> 2;
  int akc = (tid & 3) * 8;
  const unsigned short* aptr = g + (size_t)(off + m0 + ar) * HID;
  int bj = tid & 63;
  int bk = (tid >> 6) * 8;
  const float* bbase = W2 + (size_t)e * HID * DIMX + n0 + bj;

  f32x4 acc[2][2];
#pragma unroll
  for (int i = 0; i < 2; i++)
#pragma unroll
    for (int j = 0; j < 2; j++) acc[i][j] = (f32x4)0.f;

  int kg = (lane >> 4) * 8;
  int rsel = lane & 15;

  for (int ks = 0; ks < HID; ks += 32) {
    short8 av = *(const short8*)(aptr + ks + akc);
    *(short8*)&As[ar][akc] = av;
    short8 bv;
#pragma unroll
    for (int i = 0; i < 8; i++)
      bv[i] = (short)f2bf(bbase[(size_t)(ks + bk + i) * DIMX]);
    *(short8*)&Bs[bj][bk] = bv;

    __syncthreads();
    short8 af0 = *(short8*)&As[wm * 32 + rsel][kg];
    short8 af1 = *(short8*)&As[wm * 32 + 16 + rsel][kg];
    short8 bf0 = *(short8*)&Bs[wn * 32 + rsel][kg];
    short8 bf1 = *(short8*)&Bs[wn * 32 + 16 + rsel][kg];
    acc[0][0] = __builtin_amdgcn_mfma_f32_16x16x32_bf16(af0, bf0, acc[0][0], 0, 0, 0);
    acc[0][1] = __builtin_amdgcn_mfma_f32_16x16x32_bf16(af0, bf1, acc[0][1], 0, 0, 0);
    acc[1][0] = __builtin_amdgcn_mfma_f32_16x16x32_bf16(af1, bf0, acc[1][0], 0, 0, 0);
    acc[1][1] = __builtin_amdgcn_mfma_f32_16x16x32_bf16(af1, bf1, acc[1][1], 0, 0, 0);
    __syncthreads();
  }

  int crow = (lane >> 4) * 4;
  int ccol = lane & 15;
#pragma unroll
  for (int fm = 0; fm < 2; fm++) {
#pragma unroll
    for (int r = 0; r < 4; r++) {
      int m = m0 + wm * 32 + fm * 16 + crow + r;
      if (m < cnt) {
        int tok = ttok[off + m];
        float w = tw[off + m];
#pragma unroll
        for (int fn = 0; fn < 2; fn++) {
          int j = n0 + wn * 32 + fn * 16 + ccol;
          atomicAdd(&out[(size_t)tok * DIMX + j], w * acc[fm][fn][r]);
        }
      }
    }
  }
}

extern "C" void kernel_launch(void* const* d_in, const int* in_sizes, int n_in,
                              void* d_out, int out_size, void* d_ws, size_t ws_size,
                              hipStream_t stream) {
  const float* x  = (const float*)d_in[0];
  const float* Wr = (const float*)d_in[1];
  const float* br = (const float*)d_in[2];
  const float* W1 = (const float*)d_in[3];
  const float* b1 = (const float*)d_in[4];
  const float* W2 = (const float*)d_in[5];
  const float* b2 = (const float*)d_in[6];
  float* out = (float*)d_out;
  char* ws = (char*)d_ws;

  bool fast = ws_size >= WS_NEED;

  hipMemsetAsync(ws, 0, WS_ZERO_BYTES, stream);
  k_router<<<N_TOK / 4, 256, 0, stream>>>(x, Wr, br, ws);
  k_prefix<<<1, 64, 0, stream>>>(ws);
  k_scatter<<<N_TOK / 256, 256, 0, stream>>>(ws);

  if (fast) {
    k_cvtx<<<1024, 256, 0, stream>>>(x, ws);
    k_tr<<<dim3(64, 16, 8), 256, 0, stream>>>(W1, (ushortT*)(ws + WS_W1T), DIMX, HID);
    k_tr<<<dim3(16, 64, 8), 256, 0, stream>>>(W2, (ushortT*)(ws + WS_W2T), HID, DIMX);
    k_cvecn<<<dim3(256, 8), 256, 0, stream>>>(b1, b2, ws);
    k_sv<<<8, 256, 0, stream>>>(ws);
    k_base<<<N_TOK, 256, 0, stream>>>(ws, out);
    k_gemm1n<<<dim3(16, 32, 8), 256, 0, stream>>>(b1, ws);
    k_gemm2n<<<dim3(16, 8, 32), 256, 0, stream>>>(ws, out);
  } else {
    k_cvec_f<<<dim3(4, NEXP, 8), 256, 0, stream>>>(W2, b1, b2, ws);
    k_sv<<<8, 256, 0, stream>>>(ws);
    k_base<<<N_TOK, 256, 0, stream>>>(ws, out);
    k_gemm1_f<<<dim3(32, HID / 64, NEXP), 256, 0, stream>>>(x, W1, b1, ws);
    k_gemm2_f<<<dim3(32, DIMX / 64, NEXP), 256, 0, stream>>>(W2, ws, out);
  }
}